// Round 1
// baseline (105.580 us; speedup 1.0000x reference)
//
#include <hip/hip_runtime.h>
#include <math.h>

// Problem constants: B=1, L=256, D=256, H=8, DK=32, R=2
// Algebraic collapse:
//   base{Q,K,V}[j,d] = ({LN(q),k,v} @ W^T + b)[j,d]
//   e_ij = exp(-|t_i - t_j|)
//   score[h,i,j] = (1 + e_ij^2) * s_qk[h,j] / sqrt(32),
//     s_qk[h,j] = sum_dk baseQ[j,h*32+dk]*baseK[j,h*32+dk]
//   attn = softmax_j(score)            (returned as output #2)
//   ctx[h,i,dk] = sum_j attn[h,i,j]*(1+e_ij)*baseV[j,h*32+dk]
//   out = ctx_flat @ fc_w^T + fc_b + q (returned as output #1)

#define INV_TEMP 0.17677669529663687f  // 1/sqrt(32)

// ---------------- K1: LayerNorm of q -> qn ----------------
// 64 blocks x 256 threads; one wave per row, 4 f32 per lane.
__global__ __launch_bounds__(256) void k_ln(const float* __restrict__ q,
                                            const float* __restrict__ g,
                                            const float* __restrict__ b,
                                            float* __restrict__ qn) {
  const int row  = (blockIdx.x << 2) + (threadIdx.x >> 6);
  const int lane = threadIdx.x & 63;
  float4 x = ((const float4*)(q + (row << 8)))[lane];
  float s = x.x + x.y + x.z + x.w;
#pragma unroll
  for (int off = 32; off; off >>= 1) s += __shfl_xor(s, off);
  const float mu = s * 0.00390625f;  // /256
  const float d0 = x.x - mu, d1 = x.y - mu, d2 = x.z - mu, d3 = x.w - mu;
  float var = d0 * d0 + d1 * d1 + d2 * d2 + d3 * d3;
#pragma unroll
  for (int off = 32; off; off >>= 1) var += __shfl_xor(var, off);
  const float rs = rsqrtf(var * 0.00390625f + 1e-6f);
  const float4 gv = ((const float4*)g)[lane];
  const float4 bv = ((const float4*)b)[lane];
  float4 y;
  y.x = d0 * rs * gv.x + bv.x;
  y.y = d1 * rs * gv.y + bv.y;
  y.z = d2 * rs * gv.z + bv.z;
  y.w = d3 * rs * gv.w + bv.w;
  ((float4*)(qn + (row << 8)))[lane] = y;
}

// ---------------- shared GEMM tile body (NT, 256x256x256) ----------------
// 32x32 output tile per block, 256 threads, 2x2 micro-tile, k-major LDS
// (pad 34 so float2 reads are 8B-aligned and conflict-free).
__device__ __forceinline__ void gemm_body(const float* __restrict__ X,
                                          const float* __restrict__ W,
                                          const float* __restrict__ bias,
                                          const float* __restrict__ res,
                                          float* __restrict__ out) {
  __shared__ float As[32][34];  // As[k][j]
  __shared__ float Bs[32][34];  // Bs[k][o]
  const int t  = threadIdx.x;
  const int j0 = blockIdx.y << 5, o0 = blockIdx.x << 5;
  const int tx = t & 15, ty = t >> 4;
  const int lr = t >> 3, lc = (t & 7) << 2;
  float acc00 = 0.f, acc01 = 0.f, acc10 = 0.f, acc11 = 0.f;
  for (int k0 = 0; k0 < 256; k0 += 32) {
    const float4 a = *(const float4*)(X + ((j0 + lr) << 8) + k0 + lc);
    const float4 w = *(const float4*)(W + ((o0 + lr) << 8) + k0 + lc);
    if (k0) __syncthreads();  // WAR guard vs previous iter's LDS reads
    As[lc + 0][lr] = a.x; As[lc + 1][lr] = a.y;
    As[lc + 2][lr] = a.z; As[lc + 3][lr] = a.w;
    Bs[lc + 0][lr] = w.x; Bs[lc + 1][lr] = w.y;
    Bs[lc + 2][lr] = w.z; Bs[lc + 3][lr] = w.w;
    __syncthreads();
#pragma unroll
    for (int kk = 0; kk < 32; ++kk) {
      const float2 av = *(const float2*)&As[kk][ty << 1];
      const float2 bv = *(const float2*)&Bs[kk][tx << 1];
      acc00 = fmaf(av.x, bv.x, acc00);
      acc01 = fmaf(av.x, bv.y, acc01);
      acc10 = fmaf(av.y, bv.x, acc10);
      acc11 = fmaf(av.y, bv.y, acc11);
    }
  }
  const int j = j0 + (ty << 1), o = o0 + (tx << 1);
  const float b0 = bias[o], b1 = bias[o + 1];
  float r00 = 0.f, r01 = 0.f, r10 = 0.f, r11 = 0.f;
  if (res) {
    r00 = res[(j << 8) + o];       r01 = res[(j << 8) + o + 1];
    r10 = res[((j + 1) << 8) + o]; r11 = res[((j + 1) << 8) + o + 1];
  }
  out[(j << 8) + o]           = acc00 + b0 + r00;
  out[(j << 8) + o + 1]       = acc01 + b1 + r01;
  out[((j + 1) << 8) + o]     = acc10 + b0 + r10;
  out[((j + 1) << 8) + o + 1] = acc11 + b1 + r11;
}

// K2: three projection GEMMs in one dispatch (grid.z selects q/k/v)
__global__ __launch_bounds__(256) void k_gemm3(
    const float* __restrict__ qn, const float* __restrict__ kin,
    const float* __restrict__ vin, const float* __restrict__ Wq,
    const float* __restrict__ bq, const float* __restrict__ Wk,
    const float* __restrict__ bk, const float* __restrict__ Wv,
    const float* __restrict__ bv, float* __restrict__ baseQ,
    float* __restrict__ baseK, float* __restrict__ baseV) {
  if (blockIdx.z == 0)       gemm_body(qn,  Wq, bq, nullptr, baseQ);
  else if (blockIdx.z == 1)  gemm_body(kin, Wk, bk, nullptr, baseK);
  else                       gemm_body(vin, Wv, bv, nullptr, baseV);
}

// K4 (final): fc GEMM + bias + residual
__global__ __launch_bounds__(256) void k_fc(const float* __restrict__ ctxf,
                                            const float* __restrict__ fc_w,
                                            const float* __restrict__ fc_b,
                                            const float* __restrict__ q,
                                            float* __restrict__ out) {
  gemm_body(ctxf, fc_w, fc_b, q, out);
}

// ---------------- K3: fused s_qk + softmax + attn-out + ctx ----------------
// grid (32, 8): blockIdx.y = head, blockIdx.x = 8-row i-tile.
// 512 threads = 8 waves, one i-row per wave.
__global__ __launch_bounds__(512) void k_attn(const float* __restrict__ baseQ,
                                              const float* __restrict__ baseK,
                                              const float* __restrict__ baseV,
                                              const float* __restrict__ tt,
                                              float* __restrict__ attn_out,
                                              float* __restrict__ ctxf) {
  const int h  = blockIdx.y;
  const int i0 = blockIdx.x << 3;
  __shared__ float s_lds[256];   // s_qk[h, j] * invtemp
  __shared__ float P[8][256];    // per-wave attn*(1+e) row
  const int t = threadIdx.x;
  if (t < 256) {
    const float4* qr = (const float4*)(baseQ + (t << 8) + (h << 5));
    const float4* kr = (const float4*)(baseK + (t << 8) + (h << 5));
    float acc = 0.f;
#pragma unroll
    for (int u = 0; u < 8; ++u) {
      const float4 a = qr[u], b = kr[u];
      acc += a.x * b.x + a.y * b.y + a.z * b.z + a.w * b.w;
    }
    s_lds[t] = acc * INV_TEMP;
  }
  __syncthreads();

  const int w = t >> 6, lane = t & 63;
  const int i = i0 + w;
  const float ti = tt[i];
  const float4 tj = ((const float4*)tt)[lane];
  const float4 sv = ((const float4*)s_lds)[lane];
  const float e0 = __expf(-fabsf(ti - tj.x));
  const float e1 = __expf(-fabsf(ti - tj.y));
  const float e2 = __expf(-fabsf(ti - tj.z));
  const float e3 = __expf(-fabsf(ti - tj.w));
  const float sc0 = (1.f + e0 * e0) * sv.x;
  const float sc1 = (1.f + e1 * e1) * sv.y;
  const float sc2 = (1.f + e2 * e2) * sv.z;
  const float sc3 = (1.f + e3 * e3) * sv.w;
  float m = fmaxf(fmaxf(sc0, sc1), fmaxf(sc2, sc3));
#pragma unroll
  for (int off = 32; off; off >>= 1) m = fmaxf(m, __shfl_xor(m, off));
  float p0 = __expf(sc0 - m), p1 = __expf(sc1 - m);
  float p2 = __expf(sc2 - m), p3 = __expf(sc3 - m);
  float s = p0 + p1 + p2 + p3;
#pragma unroll
  for (int off = 32; off; off >>= 1) s += __shfl_xor(s, off);
  const float rinv = 1.f / s;
  p0 *= rinv; p1 *= rinv; p2 *= rinv; p3 *= rinv;
  const float4 av = make_float4(p0, p1, p2, p3);  // softmax -> output #2
  ((float4*)(attn_out + (((h << 8) + i) << 8)))[lane] = av;
  const float4 pv = make_float4(p0 * (1.f + e0), p1 * (1.f + e1),
                                p2 * (1.f + e2), p3 * (1.f + e3));
  ((float4*)P[w])[lane] = pv;  // same-wave RAW: compiler emits lgkmcnt wait

  // ctx[h,i,dk] = sum_j P[j] * baseV[j, h*32+dk]; lanes split j-range in half
  const int dk = lane & 31, half = lane >> 5;
  const float* Pr = P[w] + (half << 7);
  const float* Vp = baseV + (h << 5) + dk + ((half << 7) << 8);
  float a0 = 0.f, a1 = 0.f, a2 = 0.f, a3 = 0.f;
#pragma unroll 4
  for (int jj = 0; jj < 128; jj += 4) {
    a0 = fmaf(Pr[jj + 0], Vp[(jj + 0) << 8], a0);
    a1 = fmaf(Pr[jj + 1], Vp[(jj + 1) << 8], a1);
    a2 = fmaf(Pr[jj + 2], Vp[(jj + 2) << 8], a2);
    a3 = fmaf(Pr[jj + 3], Vp[(jj + 3) << 8], a3);
  }
  float acc = (a0 + a1) + (a2 + a3);
  acc += __shfl_xor(acc, 32);
  if (half == 0) ctxf[(i << 8) + (h << 5) + dk] = acc;
}

extern "C" void kernel_launch(void* const* d_in, const int* in_sizes, int n_in,
                              void* d_out, int out_size, void* d_ws,
                              size_t ws_size, hipStream_t stream) {
  const float* q    = (const float*)d_in[0];
  const float* k    = (const float*)d_in[1];
  const float* v    = (const float*)d_in[2];
  const float* tt   = (const float*)d_in[3];
  const float* Wq   = (const float*)d_in[4];
  const float* bq   = (const float*)d_in[5];
  const float* Wk   = (const float*)d_in[6];
  const float* bk   = (const float*)d_in[7];
  const float* Wv   = (const float*)d_in[8];
  const float* bv   = (const float*)d_in[9];
  const float* fc_w = (const float*)d_in[10];
  const float* fc_b = (const float*)d_in[11];
  const float* ln_g = (const float*)d_in[12];
  const float* ln_b = (const float*)d_in[13];

  float* out  = (float*)d_out;          // [256,256]
  float* attn = out + 65536;            // [8,256,256]

  float* ws    = (float*)d_ws;
  float* qn    = ws;                    // 65536
  float* baseQ = ws + 65536;
  float* baseK = ws + 131072;
  float* baseV = ws + 196608;
  float* ctxf  = ws + 262144;           // [i, h*32+dk]

  hipLaunchKernelGGL(k_ln, dim3(64), dim3(256), 0, stream, q, ln_g, ln_b, qn);
  hipLaunchKernelGGL(k_gemm3, dim3(8, 8, 3), dim3(256), 0, stream, qn, k, v,
                     Wq, bq, Wk, bk, Wv, bv, baseQ, baseK, baseV);
  hipLaunchKernelGGL(k_attn, dim3(32, 8), dim3(512), 0, stream, baseQ, baseK,
                     baseV, tt, attn, ctxf);
  hipLaunchKernelGGL(k_fc, dim3(8, 8), dim3(256), 0, stream, ctxf, fc_w, fc_b,
                     q, out);
}

// Round 3
// 100.432 us; speedup vs baseline: 1.0513x; 1.0513x over previous
//
#include <hip/hip_runtime.h>
#include <math.h>

// Problem: B=1, L=256, D=256, H=8, DK=32, R=2
// Algebraic collapse of the reference:
//   baseX[j,d] = ({LN(q),k,v} @ W^T + b)[j,d]
//   e_ij = exp(-|t_i - t_j|)
//   score[h,i,j] = (1 + e_ij^2) * s_qk[h,j] / sqrt(32),
//     s_qk[h,j] = sum_dk baseQ[j,h*32+dk]*baseK[j,h*32+dk]
//   attn = softmax_j(score)                      (output #2)
//   ctx[i,h*32+dk] = sum_j attn[h,i,j]*(1+e_ij)*baseV[j,h*32+dk]
//   out = ctx @ fc_w^T + fc_b + q                (output #1)

#define INV_TEMP 0.17677669529663687f  // 1/sqrt(32)

// ---- shared GEMM body: 32x32 tile, full-panel k-major LDS, 1 barrier ----
// mode 0: LN(X) then GEMM, store transposed [o][j]   (Q path)
// mode 1: GEMM, store transposed [o][j]              (K path)
// mode 2: GEMM, store natural [j][o]                 (V path)
// mode 3: GEMM, natural + bias + residual            (fc path)
__device__ __forceinline__ void gemm_panel(
    const float* __restrict__ X, const float* __restrict__ W,
    const float* __restrict__ bias, const float* __restrict__ res,
    const float* __restrict__ ln_g, const float* __restrict__ ln_b,
    float* __restrict__ out, const int mode) {
  __shared__ float As[256][33];  // k-major As[k][j]; pad 33 -> conflict-free
  __shared__ float Bs[256][33];
  const int t = threadIdx.x;
  const int j0 = blockIdx.y << 5, o0 = blockIdx.x << 5;
  const int lr = t >> 3;            // panel row 0..31
  const int cg = (t & 7) << 2;      // col offset within 32-chunk
  float4 xa[8], wb[8];
#pragma unroll
  for (int u = 0; u < 8; ++u) {     // 16 loads all in flight -> one latency
    xa[u] = *(const float4*)(X + ((j0 + lr) << 8) + (u << 5) + cg);
    wb[u] = *(const float4*)(W + ((o0 + lr) << 8) + (u << 5) + cg);
  }
  if (mode == 0) {  // row LayerNorm across the 8 lanes sharing row lr
    float s = 0.f, s2 = 0.f;
#pragma unroll
    for (int u = 0; u < 8; ++u) {
      s  += xa[u].x + xa[u].y + xa[u].z + xa[u].w;
      s2 += xa[u].x * xa[u].x + xa[u].y * xa[u].y +
            xa[u].z * xa[u].z + xa[u].w * xa[u].w;
    }
#pragma unroll
    for (int off = 1; off < 8; off <<= 1) {
      s  += __shfl_xor(s, off);
      s2 += __shfl_xor(s2, off);
    }
    const float mu = s * 0.00390625f;
    const float rs = rsqrtf(s2 * 0.00390625f - mu * mu + 1e-6f);
#pragma unroll
    for (int u = 0; u < 8; ++u) {
      const float4 gv = *(const float4*)(ln_g + (u << 5) + cg);
      const float4 bv = *(const float4*)(ln_b + (u << 5) + cg);
      xa[u].x = (xa[u].x - mu) * rs * gv.x + bv.x;
      xa[u].y = (xa[u].y - mu) * rs * gv.y + bv.y;
      xa[u].z = (xa[u].z - mu) * rs * gv.z + bv.z;
      xa[u].w = (xa[u].w - mu) * rs * gv.w + bv.w;
    }
  }
#pragma unroll
  for (int u = 0; u < 8; ++u) {  // transpose-stage; ~2-way banks (free)
    const int c = (u << 5) + cg;
    As[c + 0][lr] = xa[u].x; As[c + 1][lr] = xa[u].y;
    As[c + 2][lr] = xa[u].z; As[c + 3][lr] = xa[u].w;
    Bs[c + 0][lr] = wb[u].x; Bs[c + 1][lr] = wb[u].y;
    Bs[c + 2][lr] = wb[u].z; Bs[c + 3][lr] = wb[u].w;
  }
  __syncthreads();
  const int tx = t & 15, ty = t >> 4;
  float acc00 = 0.f, acc01 = 0.f, acc10 = 0.f, acc11 = 0.f;
#pragma unroll 16
  for (int kk = 0; kk < 256; ++kk) {
    const float2 av = *(const float2*)&As[kk][ty << 1];
    const float2 bv = *(const float2*)&Bs[kk][tx << 1];
    acc00 = fmaf(av.x, bv.x, acc00);
    acc01 = fmaf(av.x, bv.y, acc01);
    acc10 = fmaf(av.y, bv.x, acc10);
    acc11 = fmaf(av.y, bv.y, acc11);
  }
  const int j = j0 + (ty << 1), o = o0 + (tx << 1);
  const float b0 = bias[o], b1 = bias[o + 1];
  acc00 += b0; acc01 += b1; acc10 += b0; acc11 += b1;
  if (mode <= 1) {  // transposed store: T[o][j], T[o][j+1] etc.
    *(float2*)(out + (o << 8) + j)       = make_float2(acc00, acc10);
    *(float2*)(out + ((o + 1) << 8) + j) = make_float2(acc01, acc11);
  } else {
    float2 r0 = make_float2(0.f, 0.f), r1 = make_float2(0.f, 0.f);
    if (mode == 3) {
      r0 = *(const float2*)(res + (j << 8) + o);
      r1 = *(const float2*)(res + ((j + 1) << 8) + o);
    }
    *(float2*)(out + (j << 8) + o) = make_float2(acc00 + r0.x, acc01 + r0.y);
    *(float2*)(out + ((j + 1) << 8) + o) =
        make_float2(acc10 + r1.x, acc11 + r1.y);
  }
}

// K1: LN + 3 projection GEMMs, one dispatch (grid.z = q/k/v)
__global__ __launch_bounds__(256) void mha_proj_gemm3(
    const float* __restrict__ q, const float* __restrict__ kin,
    const float* __restrict__ vin, const float* __restrict__ Wq,
    const float* __restrict__ bq, const float* __restrict__ Wk,
    const float* __restrict__ bk, const float* __restrict__ Wv,
    const float* __restrict__ bv, const float* __restrict__ ln_g,
    const float* __restrict__ ln_b, float* __restrict__ baseQT,
    float* __restrict__ baseKT, float* __restrict__ baseV) {
  const int z = blockIdx.z;
  if (z == 0)
    gemm_panel(q, Wq, bq, nullptr, ln_g, ln_b, baseQT, 0);
  else if (z == 1)
    gemm_panel(kin, Wk, bk, nullptr, nullptr, nullptr, baseKT, 1);
  else
    gemm_panel(vin, Wv, bv, nullptr, nullptr, nullptr, baseV, 2);
}

// K3: fc GEMM + bias + residual
__global__ __launch_bounds__(256) void mha_fc_gemm(
    const float* __restrict__ ctxf, const float* __restrict__ fc_w,
    const float* __restrict__ fc_b, const float* __restrict__ q,
    float* __restrict__ out) {
  gemm_panel(ctxf, fc_w, fc_b, q, nullptr, nullptr, out, 3);
}

// K2: fused s_qk + softmax + attn output + ctx
// grid (32, 8): blockIdx.y = head, blockIdx.x = 8-row i-tile; 512 thr = 8 waves
__global__ __launch_bounds__(512) void mha_attn_fused(
    const float* __restrict__ baseQT, const float* __restrict__ baseKT,
    const float* __restrict__ baseV, const float* __restrict__ tt,
    float* __restrict__ attn_out, float* __restrict__ ctxf) {
  const int h = blockIdx.y;
  const int i0 = blockIdx.x << 3;
  const int t = threadIdx.x;
  __shared__ float s_lds[256];  // s_qk[h,j] * invtemp
  __shared__ float P[8][256];   // per-wave attn*(1+e)
  if (t < 256) {                // coalesced: consecutive t -> consecutive j
    const float* qc = baseQT + (h << 13) + t;
    const float* kc = baseKT + (h << 13) + t;
    float acc = 0.f;
#pragma unroll
    for (int dk = 0; dk < 32; ++dk)
      acc = fmaf(qc[dk << 8], kc[dk << 8], acc);
    s_lds[t] = acc * INV_TEMP;
  }
  __syncthreads();

  const int w = t >> 6, lane = t & 63;
  const int i = i0 + w;
  const float ti = tt[i];
  const float4 tj = ((const float4*)tt)[lane];
  const float4 sv = ((const float4*)s_lds)[lane];
  const float e0 = __expf(-fabsf(ti - tj.x));
  const float e1 = __expf(-fabsf(ti - tj.y));
  const float e2 = __expf(-fabsf(ti - tj.z));
  const float e3 = __expf(-fabsf(ti - tj.w));
  const float sc0 = (1.f + e0 * e0) * sv.x;
  const float sc1 = (1.f + e1 * e1) * sv.y;
  const float sc2 = (1.f + e2 * e2) * sv.z;
  const float sc3 = (1.f + e3 * e3) * sv.w;
  float m = fmaxf(fmaxf(sc0, sc1), fmaxf(sc2, sc3));
#pragma unroll
  for (int off = 32; off; off >>= 1) m = fmaxf(m, __shfl_xor(m, off));
  float p0 = __expf(sc0 - m), p1 = __expf(sc1 - m);
  float p2 = __expf(sc2 - m), p3 = __expf(sc3 - m);
  float s = p0 + p1 + p2 + p3;
#pragma unroll
  for (int off = 32; off; off >>= 1) s += __shfl_xor(s, off);
  const float rinv = 1.f / s;
  p0 *= rinv; p1 *= rinv; p2 *= rinv; p3 *= rinv;
  ((float4*)(attn_out + (((h << 8) + i) << 8)))[lane] =
      make_float4(p0, p1, p2, p3);
  ((float4*)P[w])[lane] = make_float4(p0 * (1.f + e0), p1 * (1.f + e1),
                                      p2 * (1.f + e2), p3 * (1.f + e3));

  // ctx[i, h*32+dk] = sum_j P[j] * baseV[j][h*32+dk]; halves of j per lane-half
  const int dk = lane & 31, half = lane >> 5;
  const float* Pr = P[w] + (half << 7);
  const float* Vp = baseV + (h << 5) + dk + (half << 15);
  float a0 = 0.f, a1 = 0.f, a2 = 0.f, a3 = 0.f;
#pragma unroll 4
  for (int jj = 0; jj < 128; jj += 4) {
    a0 = fmaf(Pr[jj + 0], Vp[(jj + 0) << 8], a0);
    a1 = fmaf(Pr[jj + 1], Vp[(jj + 1) << 8], a1);
    a2 = fmaf(Pr[jj + 2], Vp[(jj + 2) << 8], a2);
    a3 = fmaf(Pr[jj + 3], Vp[(jj + 3) << 8], a3);
  }
  float acc = (a0 + a1) + (a2 + a3);
  acc += __shfl_xor(acc, 32);
  if (half == 0) ctxf[(i << 8) + (h << 5) + dk] = acc;
}

extern "C" void kernel_launch(void* const* d_in, const int* in_sizes, int n_in,
                              void* d_out, int out_size, void* d_ws,
                              size_t ws_size, hipStream_t stream) {
  const float* q    = (const float*)d_in[0];
  const float* kin  = (const float*)d_in[1];
  const float* vin  = (const float*)d_in[2];
  const float* tt   = (const float*)d_in[3];
  const float* Wq   = (const float*)d_in[4];
  const float* bq   = (const float*)d_in[5];
  const float* Wk   = (const float*)d_in[6];
  const float* bk   = (const float*)d_in[7];
  const float* Wv   = (const float*)d_in[8];
  const float* bv   = (const float*)d_in[9];
  const float* fc_w = (const float*)d_in[10];
  const float* fc_b = (const float*)d_in[11];
  const float* ln_g = (const float*)d_in[12];
  const float* ln_b = (const float*)d_in[13];

  float* out  = (float*)d_out;   // [256,256]
  float* attn = out + 65536;     // [8,256,256]

  float* ws     = (float*)d_ws;
  float* baseQT = ws;            // [256][256] transposed [d][j]
  float* baseKT = ws + 65536;
  float* baseV  = ws + 131072;   // natural [j][d]
  float* ctxf   = ws + 196608;   // [i][h*32+dk]

  hipLaunchKernelGGL(mha_proj_gemm3, dim3(8, 8, 3), dim3(256), 0, stream, q,
                     kin, vin, Wq, bq, Wk, bk, Wv, bv, ln_g, ln_b, baseQT,
                     baseKT, baseV);
  hipLaunchKernelGGL(mha_attn_fused, dim3(32, 8), dim3(512), 0, stream,
                     baseQT, baseKT, baseV, tt, attn, ctxf);
  hipLaunchKernelGGL(mha_fc_gemm, dim3(8, 8), dim3(256), 0, stream, ctxf,
                     fc_w, fc_b, q, out);
}

// Round 5
// 96.544 us; speedup vs baseline: 1.0936x; 1.0403x over previous
//
#include <hip/hip_runtime.h>
#include <math.h>

// Problem: B=1, L=256, D=256, H=8, DK=32, R=2
// Algebraic collapse of the reference:
//   baseX[j,d] = ({LN(q),k,v} @ W^T + b)[j,d]
//   e_ij = exp(-|t_i - t_j|)
//   score[h,i,j] = (1 + e_ij^2) * s_qk[h,j] / sqrt(32),
//     s_qk[h,j] = sum_dk baseQ[j,h*32+dk]*baseK[j,h*32+dk]
//   attn = softmax_j(score)                      (output #2)
//   ctx[i,h*32+dk] = sum_j attn[h,i,j]*(1+e_ij)*baseV[j,h*32+dk]
//   out = ctx @ fc_w^T + fc_b + q                (output #1)

#define INV_TEMP 0.17677669529663687f  // 1/sqrt(32)

// ---- GEMM body: 32x32 tile, full-panel LDS, wave-split-K ----
// 256 thr = 4 waves; wave w owns K-slice [w*64, w*64+64); lane = 8x8 grid,
// each lane a 4x4 micro-tile via two ds_read_b128 per k (pad 36 -> 16B-
// aligned, conflict-free reads). Partials reduced across waves through LDS.
// mode 0: LN(X) then GEMM, store transposed [o][j]   (Q path)
// mode 1: GEMM, store transposed [o][j]              (K path)
// mode 2: GEMM, store natural [j][o]                 (V path)
// mode 3: GEMM, natural + bias + residual            (fc path)
__device__ __forceinline__ void gemm_panel(
    const float* __restrict__ X, const float* __restrict__ W,
    const float* __restrict__ bias, const float* __restrict__ res,
    const float* __restrict__ ln_g, const float* __restrict__ ln_b,
    float* __restrict__ out, const int mode) {
  __shared__ float As[256][36];      // k-major As[k][j]; 144B rows (9x16B)
  __shared__ float Bs[256][36];
  __shared__ float Red[4][32][36];   // per-wave partials
  const int t = threadIdx.x;
  const int j0 = blockIdx.y << 5, o0 = blockIdx.x << 5;
  const int lr = t >> 3;             // panel row 0..31
  const int cg = (t & 7) << 2;       // col offset within 32-chunk
  float4 xa[8], wb[8];
#pragma unroll
  for (int u = 0; u < 8; ++u) {      // 16 loads all in flight -> one latency
    xa[u] = *(const float4*)(X + ((j0 + lr) << 8) + (u << 5) + cg);
    wb[u] = *(const float4*)(W + ((o0 + lr) << 8) + (u << 5) + cg);
  }
  if (mode == 0) {  // row LayerNorm across the 8 lanes sharing row lr
    float s = 0.f, s2 = 0.f;
#pragma unroll
    for (int u = 0; u < 8; ++u) {
      s  += xa[u].x + xa[u].y + xa[u].z + xa[u].w;
      s2 += xa[u].x * xa[u].x + xa[u].y * xa[u].y +
            xa[u].z * xa[u].z + xa[u].w * xa[u].w;
    }
#pragma unroll
    for (int off = 1; off < 8; off <<= 1) {
      s  += __shfl_xor(s, off);
      s2 += __shfl_xor(s2, off);
    }
    const float mu = s * 0.00390625f;
    const float rs = rsqrtf(s2 * 0.00390625f - mu * mu + 1e-6f);
#pragma unroll
    for (int u = 0; u < 8; ++u) {
      const float4 gv = *(const float4*)(ln_g + (u << 5) + cg);
      const float4 bv = *(const float4*)(ln_b + (u << 5) + cg);
      xa[u].x = (xa[u].x - mu) * rs * gv.x + bv.x;
      xa[u].y = (xa[u].y - mu) * rs * gv.y + bv.y;
      xa[u].z = (xa[u].z - mu) * rs * gv.z + bv.z;
      xa[u].w = (xa[u].w - mu) * rs * gv.w + bv.w;
    }
  }
#pragma unroll
  for (int u = 0; u < 8; ++u) {  // transpose-stage (~4-way banks, cheap)
    const int c = (u << 5) + cg;
    As[c + 0][lr] = xa[u].x; As[c + 1][lr] = xa[u].y;
    As[c + 2][lr] = xa[u].z; As[c + 3][lr] = xa[u].w;
    Bs[c + 0][lr] = wb[u].x; Bs[c + 1][lr] = wb[u].y;
    Bs[c + 2][lr] = wb[u].z; Bs[c + 3][lr] = wb[u].w;
  }
  __syncthreads();

  const int w = t >> 6, lane = t & 63;
  const int jb = (lane >> 3) << 2;   // 4-row group within tile
  const int ob = (lane & 7) << 2;    // 4-col group within tile
  const int kbase = w << 6;
  float acc[4][4] = {{0.f}};
#pragma unroll 8
  for (int kk = 0; kk < 64; ++kk) {
    const float4 av = *(const float4*)&As[kbase + kk][jb];
    const float4 bv = *(const float4*)&Bs[kbase + kk][ob];
    acc[0][0] = fmaf(av.x, bv.x, acc[0][0]);
    acc[0][1] = fmaf(av.x, bv.y, acc[0][1]);
    acc[0][2] = fmaf(av.x, bv.z, acc[0][2]);
    acc[0][3] = fmaf(av.x, bv.w, acc[0][3]);
    acc[1][0] = fmaf(av.y, bv.x, acc[1][0]);
    acc[1][1] = fmaf(av.y, bv.y, acc[1][1]);
    acc[1][2] = fmaf(av.y, bv.z, acc[1][2]);
    acc[1][3] = fmaf(av.y, bv.w, acc[1][3]);
    acc[2][0] = fmaf(av.z, bv.x, acc[2][0]);
    acc[2][1] = fmaf(av.z, bv.y, acc[2][1]);
    acc[2][2] = fmaf(av.z, bv.z, acc[2][2]);
    acc[2][3] = fmaf(av.z, bv.w, acc[2][3]);
    acc[3][0] = fmaf(av.w, bv.x, acc[3][0]);
    acc[3][1] = fmaf(av.w, bv.y, acc[3][1]);
    acc[3][2] = fmaf(av.w, bv.z, acc[3][2]);
    acc[3][3] = fmaf(av.w, bv.w, acc[3][3]);
  }
#pragma unroll
  for (int r = 0; r < 4; ++r)
    *(float4*)&Red[w][jb + r][ob] =
        make_float4(acc[r][0], acc[r][1], acc[r][2], acc[r][3]);
  __syncthreads();

  // final: thread t -> row j = t>>3, col-quad o4 = (t&7)*4
  const int j = t >> 3, o4 = (t & 7) << 2;
  const float4 s0 = *(const float4*)&Red[0][j][o4];
  const float4 s1 = *(const float4*)&Red[1][j][o4];
  const float4 s2 = *(const float4*)&Red[2][j][o4];
  const float4 s3 = *(const float4*)&Red[3][j][o4];
  const float4 bv4 = *(const float4*)(bias + o0 + o4);
  float4 rs4;
  rs4.x = (s0.x + s1.x) + (s2.x + s3.x) + bv4.x;
  rs4.y = (s0.y + s1.y) + (s2.y + s3.y) + bv4.y;
  rs4.z = (s0.z + s1.z) + (s2.z + s3.z) + bv4.z;
  rs4.w = (s0.w + s1.w) + (s2.w + s3.w) + bv4.w;
  const int gj = j0 + j, go = o0 + o4;
  if (mode <= 1) {  // transposed store out[o][j]
    out[((go + 0) << 8) + gj] = rs4.x;
    out[((go + 1) << 8) + gj] = rs4.y;
    out[((go + 2) << 8) + gj] = rs4.z;
    out[((go + 3) << 8) + gj] = rs4.w;
  } else {
    if (mode == 3) {
      const float4 rv = *(const float4*)(res + (gj << 8) + go);
      rs4.x += rv.x; rs4.y += rv.y; rs4.z += rv.z; rs4.w += rv.w;
    }
    *(float4*)(out + (gj << 8) + go) = rs4;
  }
}

// K1: LN + 3 projection GEMMs, one dispatch (grid.z = q/k/v)
__global__ __launch_bounds__(256) void mha_proj_gemm3(
    const float* __restrict__ q, const float* __restrict__ kin,
    const float* __restrict__ vin, const float* __restrict__ Wq,
    const float* __restrict__ bq, const float* __restrict__ Wk,
    const float* __restrict__ bk, const float* __restrict__ Wv,
    const float* __restrict__ bv, const float* __restrict__ ln_g,
    const float* __restrict__ ln_b, float* __restrict__ baseQT,
    float* __restrict__ baseKT, float* __restrict__ baseV) {
  const int z = blockIdx.z;
  if (z == 0)
    gemm_panel(q, Wq, bq, nullptr, ln_g, ln_b, baseQT, 0);
  else if (z == 1)
    gemm_panel(kin, Wk, bk, nullptr, nullptr, nullptr, baseKT, 1);
  else
    gemm_panel(vin, Wv, bv, nullptr, nullptr, nullptr, baseV, 2);
}

// K3: fc GEMM + bias + residual
__global__ __launch_bounds__(256) void mha_fc_gemm(
    const float* __restrict__ ctxf, const float* __restrict__ fc_w,
    const float* __restrict__ fc_b, const float* __restrict__ q,
    float* __restrict__ out) {
  gemm_panel(ctxf, fc_w, fc_b, q, nullptr, nullptr, out, 3);
}

// K2: fused s_qk + softmax + attn output + ctx
// grid (32, 8): blockIdx.y = head, blockIdx.x = 8-row i-tile; 512 thr = 8 waves
__global__ __launch_bounds__(512) void mha_attn_fused(
    const float* __restrict__ baseQT, const float* __restrict__ baseKT,
    const float* __restrict__ baseV, const float* __restrict__ tt,
    float* __restrict__ attn_out, float* __restrict__ ctxf) {
  const int h = blockIdx.y;
  const int i0 = blockIdx.x << 3;
  const int t = threadIdx.x;
  __shared__ float s_lds[256];  // s_qk[h,j] * invtemp
  __shared__ float P[8][256];   // per-wave attn*(1+e)
  if (t < 256) {                // coalesced: consecutive t -> consecutive j
    const float* qc = baseQT + (h << 13) + t;
    const float* kc = baseKT + (h << 13) + t;
    float acc = 0.f;
#pragma unroll
    for (int dk = 0; dk < 32; ++dk)
      acc = fmaf(qc[dk << 8], kc[dk << 8], acc);
    s_lds[t] = acc * INV_TEMP;
  }
  __syncthreads();

  const int w = t >> 6, lane = t & 63;
  const int i = i0 + w;
  const float ti = tt[i];
  const float4 tj = ((const float4*)tt)[lane];
  const float4 sv = ((const float4*)s_lds)[lane];
  const float e0 = __expf(-fabsf(ti - tj.x));
  const float e1 = __expf(-fabsf(ti - tj.y));
  const float e2 = __expf(-fabsf(ti - tj.z));
  const float e3 = __expf(-fabsf(ti - tj.w));
  const float sc0 = (1.f + e0 * e0) * sv.x;
  const float sc1 = (1.f + e1 * e1) * sv.y;
  const float sc2 = (1.f + e2 * e2) * sv.z;
  const float sc3 = (1.f + e3 * e3) * sv.w;
  float m = fmaxf(fmaxf(sc0, sc1), fmaxf(sc2, sc3));
#pragma unroll
  for (int off = 32; off; off >>= 1) m = fmaxf(m, __shfl_xor(m, off));
  float p0 = __expf(sc0 - m), p1 = __expf(sc1 - m);
  float p2 = __expf(sc2 - m), p3 = __expf(sc3 - m);
  float s = p0 + p1 + p2 + p3;
#pragma unroll
  for (int off = 32; off; off >>= 1) s += __shfl_xor(s, off);
  const float rinv = 1.f / s;
  p0 *= rinv; p1 *= rinv; p2 *= rinv; p3 *= rinv;
  ((float4*)(attn_out + (((h << 8) + i) << 8)))[lane] =
      make_float4(p0, p1, p2, p3);
  ((float4*)P[w])[lane] = make_float4(p0 * (1.f + e0), p1 * (1.f + e1),
                                      p2 * (1.f + e2), p3 * (1.f + e3));

  // ctx[i, h*32+dk] = sum_j P[j] * baseV[j][h*32+dk]; halves of j per lane-half
  const int dk = lane & 31, half = lane >> 5;
  const float* Pr = P[w] + (half << 7);
  const float* Vp = baseV + (h << 5) + dk + (half << 15);
  float a0 = 0.f, a1 = 0.f, a2 = 0.f, a3 = 0.f;
#pragma unroll 4
  for (int jj = 0; jj < 128; jj += 4) {
    a0 = fmaf(Pr[jj + 0], Vp[(jj + 0) << 8], a0);
    a1 = fmaf(Pr[jj + 1], Vp[(jj + 1) << 8], a1);
    a2 = fmaf(Pr[jj + 2], Vp[(jj + 2) << 8], a2);
    a3 = fmaf(Pr[jj + 3], Vp[(jj + 3) << 8], a3);
  }
  float acc = (a0 + a1) + (a2 + a3);
  acc += __shfl_xor(acc, 32);
  if (half == 0) ctxf[(i << 8) + (h << 5) + dk] = acc;
}

extern "C" void kernel_launch(void* const* d_in, const int* in_sizes, int n_in,
                              void* d_out, int out_size, void* d_ws,
                              size_t ws_size, hipStream_t stream) {
  const float* q    = (const float*)d_in[0];
  const float* kin  = (const float*)d_in[1];
  const float* vin  = (const float*)d_in[2];
  const float* tt   = (const float*)d_in[3];
  const float* Wq   = (const float*)d_in[4];
  const float* bq   = (const float*)d_in[5];
  const float* Wk   = (const float*)d_in[6];
  const float* bk   = (const float*)d_in[7];
  const float* Wv   = (const float*)d_in[8];
  const float* bv   = (const float*)d_in[9];
  const float* fc_w = (const float*)d_in[10];
  const float* fc_b = (const float*)d_in[11];
  const float* ln_g = (const float*)d_in[12];
  const float* ln_b = (const float*)d_in[13];

  float* out  = (float*)d_out;   // [256,256]
  float* attn = out + 65536;     // [8,256,256]

  float* ws     = (float*)d_ws;
  float* baseQT = ws;            // [256][256] transposed [d][j]
  float* baseKT = ws + 65536;
  float* baseV  = ws + 131072;   // natural [j][d]
  float* ctxf   = ws + 196608;   // [i][h*32+dk]

  hipLaunchKernelGGL(mha_proj_gemm3, dim3(8, 8, 3), dim3(256), 0, stream, q,
                     kin, vin, Wq, bq, Wk, bk, Wv, bv, ln_g, ln_b, baseQT,
                     baseKT, baseV);
  hipLaunchKernelGGL(mha_attn_fused, dim3(32, 8), dim3(512), 0, stream,
                     baseQT, baseKT, baseV, tt, attn, ctxf);
  hipLaunchKernelGGL(mha_fc_gemm, dim3(8, 8), dim3(256), 0, stream, ctxf,
                     fc_w, fc_b, q, out);
}